// Round 1
// baseline (117.093 us; speedup 1.0000x reference)
//
#include <hip/hip_runtime.h>

#define H_IN   181
#define W_IN   360
#define NLAT   361
#define NLON   720
#define CIN    16
#define COUT   16
#define KSZ    3
#define NNZ    8192
#define MAXB   1024   // max nonzeros per output latitude bucket (mean ~23)

// Kernel 1: xw[k][h][y][co] = sum_c x[c][h][y] * w[co][c][k]
__global__ __launch_bounds__(256) void mix_kernel(
    const float* __restrict__ x,      // [CIN][H_IN][W_IN]
    const float* __restrict__ w,      // [COUT][CIN][KSZ]
    float* __restrict__ xw)           // [KSZ][H_IN][W_IN][COUT]
{
    __shared__ float sw[COUT * CIN * KSZ];
    const int tid = threadIdx.x;
    for (int i = tid; i < COUT * CIN * KSZ; i += blockDim.x) sw[i] = w[i];
    __syncthreads();

    const int idx = blockIdx.x * blockDim.x + tid;   // over KSZ*H_IN*W_IN
    if (idx >= KSZ * H_IN * W_IN) return;
    const int k  = idx / (H_IN * W_IN);
    const int hy = idx - k * (H_IN * W_IN);

    float acc[COUT];
#pragma unroll
    for (int co = 0; co < COUT; ++co) acc[co] = 0.f;

    for (int c = 0; c < CIN; ++c) {
        const float xv = x[c * (H_IN * W_IN) + hy];
#pragma unroll
        for (int co = 0; co < COUT; ++co)
            acc[co] += xv * sw[(co * CIN + c) * KSZ + k];
    }

    float4* dst = (float4*)(xw + (size_t)idx * COUT);
#pragma unroll
    for (int q = 0; q < 4; ++q)
        dst[q] = make_float4(acc[4*q+0], acc[4*q+1], acc[4*q+2], acc[4*q+3]);
}

// Kernel 2: gather formulation of the scatter-add.
// grid.x = NLAT * 3 (3 lon-chunks of 240), block = 256 (threads 240..255 idle in main loop)
__global__ __launch_bounds__(256) void gather_kernel(
    const float* __restrict__ xw,     // [KSZ][H_IN][W_IN][COUT]
    const float* __restrict__ bias,   // [COUT]
    const int*   __restrict__ ker_idx,
    const int*   __restrict__ row_idx,
    const int*   __restrict__ col_idx,
    const float* __restrict__ vals,
    float* __restrict__ out)          // [COUT][NLAT][NLON]
{
    const int ho    = blockIdx.x / 3;
    const int chunk = blockIdx.x % 3;
    const int tid   = threadIdx.x;

    __shared__ int   s_cnt;
    __shared__ int   s_base[MAXB];    // (k*H_IN + tin) * W_IN * COUT
    __shared__ int   s_p[MAXB];
    __shared__ float s_v[MAXB];

    if (tid == 0) s_cnt = 0;
    __syncthreads();

    // Build this latitude's bucket from the COO nonzeros.
    for (int n = tid; n < NNZ; n += 256) {
        const int c  = col_idx[n];
        const int hi = c / NLON;
        if (hi == ho) {
            const int slot = atomicAdd(&s_cnt, 1);
            if (slot < MAXB) {
                s_base[slot] = (ker_idx[n] * H_IN + row_idx[n]) * (W_IN * COUT);
                s_p[slot]    = c - hi * NLON;
                s_v[slot]    = vals[n];
            }
        }
    }
    __syncthreads();
    const int cnt = (s_cnt < MAXB) ? s_cnt : MAXB;

    if (tid >= 240) return;
    const int lo = chunk * 240 + tid;

    float acc[COUT];
#pragma unroll
    for (int co = 0; co < COUT; ++co) acc[co] = bias[co];

    for (int e = 0; e < cnt; ++e) {
        const int p = s_p[e];           // wave-uniform broadcast
        const int d = lo - p;
        if (d & 1) continue;            // parity mismatch -> no y solves (p+2y)%720==lo
        const int y = ((d < 0) ? d + NLON : d) >> 1;   // unique y in [0,360)
        const float v = s_v[e];
        const float4* src = (const float4*)(xw + s_base[e] + y * COUT);
#pragma unroll
        for (int q = 0; q < 4; ++q) {
            const float4 f = src[q];
            acc[4*q+0] += v * f.x;
            acc[4*q+1] += v * f.y;
            acc[4*q+2] += v * f.z;
            acc[4*q+3] += v * f.w;
        }
    }

#pragma unroll
    for (int co = 0; co < COUT; ++co)
        out[(co * NLAT + ho) * NLON + lo] = acc[co];
}

extern "C" void kernel_launch(void* const* d_in, const int* in_sizes, int n_in,
                              void* d_out, int out_size, void* d_ws, size_t ws_size,
                              hipStream_t stream) {
    const float* x       = (const float*)d_in[0];
    const float* weight  = (const float*)d_in[1];
    const float* bias    = (const float*)d_in[2];
    const int*   ker_idx = (const int*)d_in[3];
    const int*   row_idx = (const int*)d_in[4];
    const int*   col_idx = (const int*)d_in[5];
    const float* vals    = (const float*)d_in[6];
    float* out = (float*)d_out;
    float* xw  = (float*)d_ws;   // needs KSZ*H_IN*W_IN*COUT*4 = 12,510,720 bytes

    const int n_mix = KSZ * H_IN * W_IN;
    mix_kernel<<<(n_mix + 255) / 256, 256, 0, stream>>>(x, weight, xw);
    gather_kernel<<<NLAT * 3, 256, 0, stream>>>(xw, bias, ker_idx, row_idx,
                                                col_idx, vals, out);
}